// Round 11
// baseline (48.676 us; speedup 1.0000x reference)
//
#include <hip/hip_runtime.h>

namespace {
constexpr int Wd = 160, Hd = 192, Dd = 160, Bd = 2;
constexpr int HW = Hd * Wd;
constexpr int THREADS = 256;               // 4 waves
constexpr int ROWS_OUT = 6;                // output rows per block
constexpr int ROWS_LDS = 8;                // staged rows incl. h-halo
constexpr int RS = 164;                    // LDS row stride (floats)
constexpr int STRIPS = 40;                 // float4 strips per row
constexpr int CTHREADS = ROWS_OUT * STRIPS;   // 240 compute threads
constexpr int TASKS = 2 * ROWS_LDS * STRIPS;  // 640 staging tasks
constexpr int DCHUNK = 5;                  // -> grid 2048 = 8/CU demanded, 7 resident
constexpr int NCHUNK = Dd / DCHUNK;        // 32
constexpr int RGROUPS = Hd / ROWS_OUT;     // 32
constexpr float EPS = 1e-8f;
}

__device__ __forceinline__ float dpp_up1(float v) {   // lane i <- lane i-1
  return __int_as_float(__builtin_amdgcn_update_dpp(
      0, __float_as_int(v), 0x138, 0xF, 0xF, true));  // wave_shr:1
}
__device__ __forceinline__ float dpp_dn1(float v) {   // lane i <- lane i+1
  return __int_as_float(__builtin_amdgcn_update_dpp(
      0, __float_as_int(v), 0x130, 0xF, 0xF, true));  // wave_shl:1
}

__global__ __launch_bounds__(THREADS) void sobel_loss_kernel(
    const float* __restrict__ pred, const float* __restrict__ targ,
    float* __restrict__ out) {
  // staged separable row partials: sw = [1,2,1]_w * x, dw = [-1,0,1]_w * x
  __shared__ float lsw[2][ROWS_LDS][RS];   // 10.5 KB
  __shared__ float ldw[2][ROWS_LDS][RS];   // 10.5 KB
  const int tid = threadIdx.x;
  const int lane = tid & 63;
  const int h0 = blockIdx.x * ROWS_OUT;
  const int d0 = blockIdx.y * DCHUNK;
  const size_t volOff = (size_t)blockIdx.z * Dd * HW;
  const float* pb = pred + volOff;
  const float* tb = targ + volOff;

  // ---- staging task decode (2.5 tasks/thread, loop-invariant) ----
  // task i -> tensor t_, row r8, strip s ; s is lane-contiguous => DPP halo
  const float* gs[3];
  float* psw[3];
  float* pdw[3];
  bool sok[3], rok[3], zL[3], zR[3], pL[3], pR[3];
#pragma unroll
  for (int u = 0; u < 3; ++u) {
    const int i = tid + 256 * u;
    const bool ok = (i < TASKS);
    const int ic = ok ? i : 0;
    const int t_ = ic / (ROWS_LDS * STRIPS);
    const int rem = ic - t_ * (ROWS_LDS * STRIPS);
    const int r8 = rem / STRIPS, s = rem - r8 * STRIPS;
    const int hh = h0 - 1 + r8;
    const bool rv = ok && ((unsigned)hh < (unsigned)Hd);
    sok[u] = ok;
    rok[u] = rv;
    zL[u] = (s == 0);                      // w zero-pad left
    zR[u] = (s == STRIPS - 1);             // w zero-pad right
    pL[u] = ok && (lane == 0) && (s != 0);            // wave-boundary patch
    pR[u] = ok && (lane == 63) && (s != STRIPS - 1);  // wave-boundary patch
    gs[u] = (t_ ? tb : pb) + (size_t)(rv ? hh : 0) * Wd + s * 4;
    psw[u] = &lsw[t_][r8][s * 4];
    pdw[u] = &ldw[t_][r8][s * 4];
  }

  float4 m[3];
  float hl[3], hr[3];
  auto GLOAD = [&](int d) {   // float4-only + <=2 exec-masked scalars per wave
    const bool dok = (unsigned)d < (unsigned)Dd;
    const size_t so = (size_t)d * HW;
#pragma unroll
    for (int u = 0; u < 3; ++u) {
      float4 v = make_float4(0.f, 0.f, 0.f, 0.f);
      float a = 0.f, b = 0.f;
      if (dok && rok[u]) {
        v = *reinterpret_cast<const float4*>(gs[u] + so);
        if (pL[u]) a = gs[u][so - 1];
        if (pR[u]) b = gs[u][so + 4];
      }
      m[u] = v; hl[u] = a; hr[u] = b;
    }
  };

  auto STAGE = [&]() {   // w-conv once per input row, write sw/dw to LDS
#pragma unroll
    for (int u = 0; u < 3; ++u) {
      float xl = dpp_up1(m[u].w);          // lane-1 holds x[4s-4..4s-1]
      float xr = dpp_dn1(m[u].x);          // lane+1 holds x[4s+4..4s+7]
      if (zL[u]) xl = 0.f;
      if (pL[u]) xl = hl[u];
      if (zR[u]) xr = 0.f;
      if (pR[u]) xr = hr[u];
      const float x0 = xl, x1 = m[u].x, x2 = m[u].y, x3 = m[u].z,
                  x4 = m[u].w, x5 = xr;
      float4 swv, dwv;
      swv.x = fmaf(2.f, x1, x0 + x2);  dwv.x = x2 - x0;
      swv.y = fmaf(2.f, x2, x1 + x3);  dwv.y = x3 - x1;
      swv.z = fmaf(2.f, x3, x2 + x4);  dwv.z = x4 - x2;
      swv.w = fmaf(2.f, x4, x3 + x5);  dwv.w = x5 - x3;
      if (sok[u]) {
        *reinterpret_cast<float4*>(psw[u]) = swv;
        *reinterpret_cast<float4*>(pdw[u]) = dwv;
      }
    }
  };

  // ---- compute decode: output row cr (0..5), strip cs (0..39) ----
  const int cr = tid / STRIPS;
  const int cs4 = (tid - cr * STRIPS) * 4;
  const bool is_c = (tid < CTHREADS);

  // rolling state [slot][tensor][j]
  float A[3][2][4], B[3][2][4], C[3][2][4];

  auto HCONV = [&](int slot) {   // h-conv only: 6 b128 reads + 12 VALU / tensor
#pragma unroll
    for (int t_ = 0; t_ < 2; ++t_) {
      const float4 sm = *reinterpret_cast<const float4*>(&lsw[t_][cr][cs4]);
      const float4 s0 = *reinterpret_cast<const float4*>(&lsw[t_][cr + 1][cs4]);
      const float4 sp = *reinterpret_cast<const float4*>(&lsw[t_][cr + 2][cs4]);
      const float4 dm = *reinterpret_cast<const float4*>(&ldw[t_][cr][cs4]);
      const float4 dd = *reinterpret_cast<const float4*>(&ldw[t_][cr + 1][cs4]);
      const float4 dp = *reinterpret_cast<const float4*>(&ldw[t_][cr + 2][cs4]);
      const float smv[4] = {sm.x, sm.y, sm.z, sm.w};
      const float s0v[4] = {s0.x, s0.y, s0.z, s0.w};
      const float spv[4] = {sp.x, sp.y, sp.z, sp.w};
      const float dmv[4] = {dm.x, dm.y, dm.z, dm.w};
      const float ddv[4] = {dd.x, dd.y, dd.z, dd.w};
      const float dpv[4] = {dp.x, dp.y, dp.z, dp.w};
#pragma unroll
      for (int j = 0; j < 4; ++j) {
        A[slot][t_][j] = fmaf(2.f, s0v[j], smv[j] + spv[j]);
        B[slot][t_][j] = fmaf(2.f, ddv[j], dmv[j] + dpv[j]);
        C[slot][t_][j] = spv[j] - smv[j];
      }
    }
  };

  float acc = 0.f;

  // ---- prologue: slices d0-1 (slot0) and d0 (slot1) ----
  GLOAD(d0 - 1);
  STAGE(); GLOAD(d0); __syncthreads();
  if (is_c) HCONV(0);
  __syncthreads();
  STAGE(); GLOAD(d0 + 1); __syncthreads();
  if (is_c) HCONV(1);
  __syncthreads();

  // ---- main loop, fully unrolled: output slice d0+k ----
#pragma unroll
  for (int k = 0; k < DCHUNK; ++k) {
    STAGE();                               // LDS <- slice d0+1+k (loaded last iter)
    if (k < DCHUNK - 1) GLOAD(d0 + 2 + k); // issue next; consumed next iter top
    __syncthreads();
    const int i0 = k % 3, i1 = (k + 1) % 3, i2 = (k + 2) % 3;
    if (is_c) {
      HCONV(i2);                           // state <- slice d0+1+k
#pragma unroll
      for (int j = 0; j < 4; ++j) {
        float gx = B[i0][0][j] + 2.f * B[i1][0][j] + B[i2][0][j];
        float gy = C[i0][0][j] + 2.f * C[i1][0][j] + C[i2][0][j];
        float gz = A[i2][0][j] - A[i0][0][j];
        const float pm = sqrtf(fmaf(gx, gx, fmaf(gy, gy, fmaf(gz, gz, EPS))));
        gx = B[i0][1][j] + 2.f * B[i1][1][j] + B[i2][1][j];
        gy = C[i0][1][j] + 2.f * C[i1][1][j] + C[i2][1][j];
        gz = A[i2][1][j] - A[i0][1][j];
        const float tm = sqrtf(fmaf(gx, gx, fmaf(gy, gy, fmaf(gz, gz, EPS))));
        acc += fabsf(pm - tm);
      }
    }
    __syncthreads();
  }

  // ---- reduction: wave shfl -> LDS -> one atomic per block ----
  float sred = acc;
#pragma unroll
  for (int off = 32; off > 0; off >>= 1) sred += __shfl_down(sred, off, 64);
  __shared__ float wsum[THREADS / 64];
  const int wid = tid >> 6;
  if (lane == 0) wsum[wid] = sred;
  __syncthreads();
  if (tid == 0) {
    float t = 0.f;
#pragma unroll
    for (int i = 0; i < THREADS / 64; ++i) t += wsum[i];
    atomicAdd(out, t * (1.0f / (float)((size_t)Bd * Dd * Hd * Wd)));
  }
}

extern "C" void kernel_launch(void* const* d_in, const int* in_sizes, int n_in,
                              void* d_out, int out_size, void* d_ws, size_t ws_size,
                              hipStream_t stream) {
  const float* pred = (const float*)d_in[0];
  const float* targ = (const float*)d_in[1];
  float* out = (float*)d_out;
  (void)in_sizes; (void)n_in; (void)out_size; (void)d_ws; (void)ws_size;

  hipMemsetAsync(out, 0, sizeof(float), stream);
  dim3 grid(RGROUPS, NCHUNK, Bd);
  sobel_loss_kernel<<<grid, THREADS, 0, stream>>>(pred, targ, out);
}

// Round 12
// 43.853 us; speedup vs baseline: 1.1100x; 1.1100x over previous
//
#include <hip/hip_runtime.h>

namespace {
constexpr int Wd = 160, Hd = 192, Dd = 160, Bd = 2;
constexpr int HW = Hd * Wd;
constexpr int THREADS = 256;               // 4 waves
constexpr int ROWS_OUT = 6;                // output rows per block
constexpr int ROWS_LDS = 8;                // staged rows incl. h-halo
constexpr int RS = 164;                    // LDS row stride (floats)
constexpr int STRIPS = 40;                 // float4 strips per row
constexpr int CTHREADS = ROWS_OUT * STRIPS;   // 240 compute threads
constexpr int TASKS = 2 * ROWS_LDS * STRIPS;  // 640 staging tasks
constexpr int DCHUNK = 10;                 // grid 1024 (proven best, R10)
constexpr int NCHUNK = Dd / DCHUNK;        // 16
constexpr int RGROUPS = Hd / ROWS_OUT;     // 32
constexpr float EPS = 1e-8f;
}

__device__ __forceinline__ float dpp_up1(float v) {   // lane i <- lane i-1
  return __int_as_float(__builtin_amdgcn_update_dpp(
      0, __float_as_int(v), 0x138, 0xF, 0xF, true));  // wave_shr:1
}
__device__ __forceinline__ float dpp_dn1(float v) {   // lane i <- lane i+1
  return __int_as_float(__builtin_amdgcn_update_dpp(
      0, __float_as_int(v), 0x130, 0xF, 0xF, true));  // wave_shl:1
}

__global__ __launch_bounds__(THREADS) void sobel_loss_kernel(
    const float* __restrict__ pred, const float* __restrict__ targ,
    float* __restrict__ out) {
  // staged separable row partials: sw = [1,2,1]_w * x, dw = [-1,0,1]_w * x
  __shared__ float lsw[2][ROWS_LDS][RS];   // 10.5 KB
  __shared__ float ldw[2][ROWS_LDS][RS];   // 10.5 KB
  const int tid = threadIdx.x;
  const int lane = tid & 63;
  const int h0 = blockIdx.x * ROWS_OUT;
  const int d0 = blockIdx.y * DCHUNK;
  const size_t volOff = (size_t)blockIdx.z * Dd * HW;
  const float* pb = pred + volOff;
  const float* tb = targ + volOff;

  // ---- staging task decode (2.5 tasks/thread, loop-invariant) ----
  const float* gs[3];
  float* psw[3];
  float* pdw[3];
  bool sok[3], rok[3], zL[3], zR[3], pL[3], pR[3];
#pragma unroll
  for (int u = 0; u < 3; ++u) {
    const int i = tid + 256 * u;
    const bool ok = (i < TASKS);
    const int ic = ok ? i : 0;
    const int t_ = ic / (ROWS_LDS * STRIPS);
    const int rem = ic - t_ * (ROWS_LDS * STRIPS);
    const int r8 = rem / STRIPS, s = rem - r8 * STRIPS;
    const int hh = h0 - 1 + r8;
    const bool rv = ok && ((unsigned)hh < (unsigned)Hd);
    sok[u] = ok;
    rok[u] = rv;
    zL[u] = (s == 0);
    zR[u] = (s == STRIPS - 1);
    pL[u] = ok && (lane == 0) && (s != 0);
    pR[u] = ok && (lane == 63) && (s != STRIPS - 1);
    gs[u] = (t_ ? tb : pb) + (size_t)(rv ? hh : 0) * Wd + s * 4;
    psw[u] = &lsw[t_][r8][s * 4];
    pdw[u] = &ldw[t_][r8][s * 4];
  }

  // two prefetch register sets (ping-pong, 2-slice-deep pipeline)
  float4 mA[3], mB[3];
  float hlA[3], hrA[3], hlB[3], hrB[3];

  auto GLOADany = [&](int d, float4 (&m)[3], float (&hl)[3], float (&hr)[3]) {
    const bool dok = (unsigned)d < (unsigned)Dd;
    const size_t so = (size_t)d * HW;
#pragma unroll
    for (int u = 0; u < 3; ++u) {
      float4 v = make_float4(0.f, 0.f, 0.f, 0.f);
      float a = 0.f, b = 0.f;
      if (dok && rok[u]) {
        v = *reinterpret_cast<const float4*>(gs[u] + so);
        if (pL[u]) a = gs[u][so - 1];
        if (pR[u]) b = gs[u][so + 4];
      }
      m[u] = v; hl[u] = a; hr[u] = b;
    }
  };

  auto STAGEany = [&](const float4 (&m)[3], const float (&hl)[3],
                      const float (&hr)[3]) {
#pragma unroll
    for (int u = 0; u < 3; ++u) {
      float xl = dpp_up1(m[u].w);
      float xr = dpp_dn1(m[u].x);
      if (zL[u]) xl = 0.f;
      if (pL[u]) xl = hl[u];
      if (zR[u]) xr = 0.f;
      if (pR[u]) xr = hr[u];
      const float x0 = xl, x1 = m[u].x, x2 = m[u].y, x3 = m[u].z,
                  x4 = m[u].w, x5 = xr;
      float4 swv, dwv;
      swv.x = fmaf(2.f, x1, x0 + x2);  dwv.x = x2 - x0;
      swv.y = fmaf(2.f, x2, x1 + x3);  dwv.y = x3 - x1;
      swv.z = fmaf(2.f, x3, x2 + x4);  dwv.z = x4 - x2;
      swv.w = fmaf(2.f, x4, x3 + x5);  dwv.w = x5 - x3;
      if (sok[u]) {
        *reinterpret_cast<float4*>(psw[u]) = swv;
        *reinterpret_cast<float4*>(pdw[u]) = dwv;
      }
    }
  };

  // ---- compute decode: output row cr (0..5), strip cs (0..39) ----
  const int cr = tid / STRIPS;
  const int cs4 = (tid - cr * STRIPS) * 4;
  const bool is_c = (tid < CTHREADS);

  // rolling state [slot][tensor][j]
  float A[3][2][4], B[3][2][4], C[3][2][4];

  auto HCONV = [&](int slot) {
#pragma unroll
    for (int t_ = 0; t_ < 2; ++t_) {
      const float4 sm = *reinterpret_cast<const float4*>(&lsw[t_][cr][cs4]);
      const float4 s0 = *reinterpret_cast<const float4*>(&lsw[t_][cr + 1][cs4]);
      const float4 sp = *reinterpret_cast<const float4*>(&lsw[t_][cr + 2][cs4]);
      const float4 dm = *reinterpret_cast<const float4*>(&ldw[t_][cr][cs4]);
      const float4 dd = *reinterpret_cast<const float4*>(&ldw[t_][cr + 1][cs4]);
      const float4 dp = *reinterpret_cast<const float4*>(&ldw[t_][cr + 2][cs4]);
      const float smv[4] = {sm.x, sm.y, sm.z, sm.w};
      const float s0v[4] = {s0.x, s0.y, s0.z, s0.w};
      const float spv[4] = {sp.x, sp.y, sp.z, sp.w};
      const float dmv[4] = {dm.x, dm.y, dm.z, dm.w};
      const float ddv[4] = {dd.x, dd.y, dd.z, dd.w};
      const float dpv[4] = {dp.x, dp.y, dp.z, dp.w};
#pragma unroll
      for (int j = 0; j < 4; ++j) {
        A[slot][t_][j] = fmaf(2.f, s0v[j], smv[j] + spv[j]);
        B[slot][t_][j] = fmaf(2.f, ddv[j], dmv[j] + dpv[j]);
        C[slot][t_][j] = spv[j] - smv[j];
      }
    }
  };

  float acc = 0.f;

  // ---- prologue: 2-deep pipeline fill ----
  GLOADany(d0 - 1, mA, hlA, hrA);
  GLOADany(d0,     mB, hlB, hrB);
  STAGEany(mA, hlA, hrA);                 // LDS <- d0-1
  GLOADany(d0 + 1, mA, hlA, hrA);         // 2-ahead
  __syncthreads();
  if (is_c) HCONV(0);                     // state0 <- d0-1
  __syncthreads();
  STAGEany(mB, hlB, hrB);                 // LDS <- d0
  GLOADany(d0 + 2, mB, hlB, hrB);
  __syncthreads();
  if (is_c) HCONV(1);                     // state1 <- d0
  __syncthreads();

  // ---- main loop, fully unrolled: output slice d0+k ----
#pragma unroll
  for (int k = 0; k < DCHUNK; ++k) {
    if ((k & 1) == 0) {
      STAGEany(mA, hlA, hrA);             // LDS <- slice d0+1+k (loaded 2 iters ago)
      if (k < DCHUNK - 2) GLOADany(d0 + 3 + k, mA, hlA, hrA);
    } else {
      STAGEany(mB, hlB, hrB);
      if (k < DCHUNK - 2) GLOADany(d0 + 3 + k, mB, hlB, hrB);
    }
    __syncthreads();
    const int i0 = k % 3, i1 = (k + 1) % 3, i2 = (k + 2) % 3;
    if (is_c) {
      HCONV(i2);                          // state <- slice d0+1+k
#pragma unroll
      for (int j = 0; j < 4; ++j) {
        float gx = B[i0][0][j] + 2.f * B[i1][0][j] + B[i2][0][j];
        float gy = C[i0][0][j] + 2.f * C[i1][0][j] + C[i2][0][j];
        float gz = A[i2][0][j] - A[i0][0][j];
        const float pm = sqrtf(fmaf(gx, gx, fmaf(gy, gy, fmaf(gz, gz, EPS))));
        gx = B[i0][1][j] + 2.f * B[i1][1][j] + B[i2][1][j];
        gy = C[i0][1][j] + 2.f * C[i1][1][j] + C[i2][1][j];
        gz = A[i2][1][j] - A[i0][1][j];
        const float tm = sqrtf(fmaf(gx, gx, fmaf(gy, gy, fmaf(gz, gz, EPS))));
        acc += fabsf(pm - tm);
      }
    }
    __syncthreads();
  }

  // ---- reduction: wave shfl -> LDS -> one atomic per block ----
  float sred = acc;
#pragma unroll
  for (int off = 32; off > 0; off >>= 1) sred += __shfl_down(sred, off, 64);
  __shared__ float wsum[THREADS / 64];
  const int wid = tid >> 6;
  if (lane == 0) wsum[wid] = sred;
  __syncthreads();
  if (tid == 0) {
    float t = 0.f;
#pragma unroll
    for (int i = 0; i < THREADS / 64; ++i) t += wsum[i];
    atomicAdd(out, t * (1.0f / (float)((size_t)Bd * Dd * Hd * Wd)));
  }
}

extern "C" void kernel_launch(void* const* d_in, const int* in_sizes, int n_in,
                              void* d_out, int out_size, void* d_ws, size_t ws_size,
                              hipStream_t stream) {
  const float* pred = (const float*)d_in[0];
  const float* targ = (const float*)d_in[1];
  float* out = (float*)d_out;
  (void)in_sizes; (void)n_in; (void)out_size; (void)d_ws; (void)ws_size;

  hipMemsetAsync(out, 0, sizeof(float), stream);
  dim3 grid(RGROUPS, NCHUNK, Bd);
  sobel_loss_kernel<<<grid, THREADS, 0, stream>>>(pred, targ, out);
}

// Round 13
// 38.437 us; speedup vs baseline: 1.2664x; 1.1409x over previous
//
#include <hip/hip_runtime.h>

namespace {
constexpr int Wd = 160, Hd = 192, Dd = 160, Bd = 2;
constexpr int HW = Hd * Wd;
constexpr int THREADS = 256;               // 4 waves
constexpr int ROWS_OUT = 6;                // output rows per block
constexpr int ROWS_LDS = 8;                // staged rows incl. h-halo
constexpr int RS = 164;                    // LDS row stride (floats)
constexpr int STRIPS = 40;                 // float4 strips per row
constexpr int CTHREADS = ROWS_OUT * STRIPS;   // 240 compute threads
constexpr int TASKS = 2 * ROWS_LDS * STRIPS;  // 640 staging tasks
constexpr int DCHUNK = 10;                 // grid 1024 (proven best, R10)
constexpr int NCHUNK = Dd / DCHUNK;        // 16
constexpr int RGROUPS = Hd / ROWS_OUT;     // 32
constexpr float EPS = 1e-8f;
}

using v4f = __attribute__((ext_vector_type(4))) float;

__device__ __forceinline__ float dpp_up1(float v) {   // lane i <- lane i-1
  return __int_as_float(__builtin_amdgcn_update_dpp(
      0, __float_as_int(v), 0x138, 0xF, 0xF, true));  // wave_shr:1
}
__device__ __forceinline__ float dpp_dn1(float v) {   // lane i <- lane i+1
  return __int_as_float(__builtin_amdgcn_update_dpp(
      0, __float_as_int(v), 0x130, 0xF, 0xF, true));  // wave_shl:1
}

__global__ __launch_bounds__(THREADS) void sobel_loss_kernel(
    const float* __restrict__ pred, const float* __restrict__ targ,
    float* __restrict__ out) {
  // staged separable row partials: sw = [1,2,1]_w * x, dw = [-1,0,1]_w * x
  __shared__ float lsw[2][ROWS_LDS][RS];   // 10.5 KB
  __shared__ float ldw[2][ROWS_LDS][RS];   // 10.5 KB
  const int tid = threadIdx.x;
  const int lane = tid & 63;
  const int h0 = blockIdx.x * ROWS_OUT;
  const int d0 = blockIdx.y * DCHUNK;
  const size_t volOff = (size_t)blockIdx.z * Dd * HW;
  const float* pb = pred + volOff;
  const float* tb = targ + volOff;

  // ---- staging task decode (2.5 tasks/thread, loop-invariant) ----
  const float* gs[3];
  float* psw[3];
  float* pdw[3];
  bool sok[3], rok[3], zL[3], zR[3], pL[3], pR[3];
#pragma unroll
  for (int u = 0; u < 3; ++u) {
    const int i = tid + 256 * u;
    const bool ok = (i < TASKS);
    const int ic = ok ? i : 0;
    const int t_ = ic / (ROWS_LDS * STRIPS);
    const int rem = ic - t_ * (ROWS_LDS * STRIPS);
    const int r8 = rem / STRIPS, s = rem - r8 * STRIPS;
    const int hh = h0 - 1 + r8;
    const bool rv = ok && ((unsigned)hh < (unsigned)Hd);
    sok[u] = ok;
    rok[u] = rv;
    zL[u] = (s == 0);
    zR[u] = (s == STRIPS - 1);
    pL[u] = ok && (lane == 0) && (s != 0);
    pR[u] = ok && (lane == 63) && (s != STRIPS - 1);
    gs[u] = (t_ ? tb : pb) + (size_t)(rv ? hh : 0) * Wd + s * 4;
    psw[u] = &lsw[t_][r8][s * 4];
    pdw[u] = &ldw[t_][r8][s * 4];
  }

  float4 m[3];
  float hl[3], hr[3];
  auto GLOAD = [&](int d) {   // float4-only + <=2 exec-masked scalars per wave
    const bool dok = (unsigned)d < (unsigned)Dd;
    const size_t so = (size_t)d * HW;
#pragma unroll
    for (int u = 0; u < 3; ++u) {
      float4 v = make_float4(0.f, 0.f, 0.f, 0.f);
      float a = 0.f, b = 0.f;
      if (dok && rok[u]) {
        v = *reinterpret_cast<const float4*>(gs[u] + so);
        if (pL[u]) a = gs[u][so - 1];
        if (pR[u]) b = gs[u][so + 4];
      }
      m[u] = v; hl[u] = a; hr[u] = b;
    }
  };

  auto STAGE = [&]() {   // w-conv once per input row, write sw/dw to LDS
#pragma unroll
    for (int u = 0; u < 3; ++u) {
      float xl = dpp_up1(m[u].w);          // lane-1 holds x[4s-4..4s-1]
      float xr = dpp_dn1(m[u].x);          // lane+1 holds x[4s+4..4s+7]
      if (zL[u]) xl = 0.f;
      if (pL[u]) xl = hl[u];
      if (zR[u]) xr = 0.f;
      if (pR[u]) xr = hr[u];
      const float x0 = xl, x1 = m[u].x, x2 = m[u].y, x3 = m[u].z,
                  x4 = m[u].w, x5 = xr;
      float4 swv, dwv;
      swv.x = fmaf(2.f, x1, x0 + x2);  dwv.x = x2 - x0;
      swv.y = fmaf(2.f, x2, x1 + x3);  dwv.y = x3 - x1;
      swv.z = fmaf(2.f, x3, x2 + x4);  dwv.z = x4 - x2;
      swv.w = fmaf(2.f, x4, x3 + x5);  dwv.w = x5 - x3;
      if (sok[u]) {
        *reinterpret_cast<float4*>(psw[u]) = swv;
        *reinterpret_cast<float4*>(pdw[u]) = dwv;
      }
    }
  };

  // ---- compute decode: output row cr (0..5), strip cs (0..39) ----
  const int cr = tid / STRIPS;
  const int cs4 = (tid - cr * STRIPS) * 4;
  const bool is_c = (tid < CTHREADS);

  // rolling state [slot][tensor] as 4-wide vectors -> v_pk_* math
  v4f A[3][2], B[3][2], C[3][2];

  auto HCONV = [&](int slot) {
#pragma unroll
    for (int t_ = 0; t_ < 2; ++t_) {
      const v4f sm = *reinterpret_cast<const v4f*>(&lsw[t_][cr][cs4]);
      const v4f s0 = *reinterpret_cast<const v4f*>(&lsw[t_][cr + 1][cs4]);
      const v4f sp = *reinterpret_cast<const v4f*>(&lsw[t_][cr + 2][cs4]);
      const v4f dm = *reinterpret_cast<const v4f*>(&ldw[t_][cr][cs4]);
      const v4f dd = *reinterpret_cast<const v4f*>(&ldw[t_][cr + 1][cs4]);
      const v4f dp = *reinterpret_cast<const v4f*>(&ldw[t_][cr + 2][cs4]);
      A[slot][t_] = s0 * 2.f + (sm + sp);
      B[slot][t_] = dd * 2.f + (dm + dp);
      C[slot][t_] = sp - sm;
    }
  };

  v4f accv = {0.f, 0.f, 0.f, 0.f};

  // ---- prologue: slices d0-1 (slot0) and d0 (slot1) ----
  GLOAD(d0 - 1);
  STAGE(); GLOAD(d0); __syncthreads();
  if (is_c) HCONV(0);
  __syncthreads();
  STAGE(); GLOAD(d0 + 1); __syncthreads();
  if (is_c) HCONV(1);
  __syncthreads();

  // ---- main loop, fully unrolled: output slice d0+k ----
#pragma unroll
  for (int k = 0; k < DCHUNK; ++k) {
    STAGE();                               // LDS <- slice d0+1+k (loaded last iter)
    if (k < DCHUNK - 1) GLOAD(d0 + 2 + k); // issue next; consumed next iter top
    __syncthreads();
    const int i0 = k % 3, i1 = (k + 1) % 3, i2 = (k + 2) % 3;
    if (is_c) {
      HCONV(i2);                           // state <- slice d0+1+k
      const v4f gx0 = B[i1][0] * 2.f + (B[i0][0] + B[i2][0]);
      const v4f gy0 = C[i1][0] * 2.f + (C[i0][0] + C[i2][0]);
      const v4f gz0 = A[i2][0] - A[i0][0];
      const v4f q0 = gx0 * gx0 + gy0 * gy0 + gz0 * gz0 + EPS;
      const v4f gx1 = B[i1][1] * 2.f + (B[i0][1] + B[i2][1]);
      const v4f gy1 = C[i1][1] * 2.f + (C[i0][1] + C[i2][1]);
      const v4f gz1 = A[i2][1] - A[i0][1];
      const v4f q1 = gx1 * gx1 + gy1 * gy1 + gz1 * gz1 + EPS;
      v4f dd_;
#pragma unroll
      for (int j = 0; j < 4; ++j)
        dd_[j] = __builtin_amdgcn_sqrtf(q0[j]) - __builtin_amdgcn_sqrtf(q1[j]);
#pragma unroll
      for (int j = 0; j < 4; ++j) dd_[j] = fabsf(dd_[j]);
      accv += dd_;
    }
    __syncthreads();
  }

  // ---- reduction: wave shfl -> LDS -> one atomic per block ----
  float sred = accv.x + accv.y + accv.z + accv.w;
#pragma unroll
  for (int off = 32; off > 0; off >>= 1) sred += __shfl_down(sred, off, 64);
  __shared__ float wsum[THREADS / 64];
  const int wid = tid >> 6;
  if (lane == 0) wsum[wid] = sred;
  __syncthreads();
  if (tid == 0) {
    float t = 0.f;
#pragma unroll
    for (int i = 0; i < THREADS / 64; ++i) t += wsum[i];
    atomicAdd(out, t * (1.0f / (float)((size_t)Bd * Dd * Hd * Wd)));
  }
}

extern "C" void kernel_launch(void* const* d_in, const int* in_sizes, int n_in,
                              void* d_out, int out_size, void* d_ws, size_t ws_size,
                              hipStream_t stream) {
  const float* pred = (const float*)d_in[0];
  const float* targ = (const float*)d_in[1];
  float* out = (float*)d_out;
  (void)in_sizes; (void)n_in; (void)out_size; (void)d_ws; (void)ws_size;

  hipMemsetAsync(out, 0, sizeof(float), stream);
  dim3 grid(RGROUPS, NCHUNK, Bd);
  sobel_loss_kernel<<<grid, THREADS, 0, stream>>>(pred, targ, out);
}